// Round 2
// baseline (380.260 us; speedup 1.0000x reference)
//
#include <hip/hip_runtime.h>
#include <cstdint>
#include <cstddef>

#define CIN  4
#define COUT 8
#define NROT 24

#define TD 4
#define TH 8
#define TW 32

__global__ __launch_bounds__(256)
void convz3p24_kernel(const float* __restrict__ xin,
                      const float* __restrict__ weight,
                      const float* __restrict__ bias,
                      float* __restrict__ out) {
  // LDS: x tile [ch][d+2][h+2][w+2 (pad->36)] + rotated weights [o][i][27 (pad->28)]
  __shared__ float lds_x[CIN][TD + 2][TH + 2][TW + 4];   // 4*6*10*36 = 8640 f = 34.6 KB
  __shared__ float lds_w[COUT][CIN][28];                 // 896 f = 3.6 KB

  const int tid = threadIdx.x;
  int bid = blockIdx.x;
  const int wt = bid & 1;  bid >>= 1;   // 2 w-tiles
  const int ht = bid & 7;  bid >>= 3;   // 8 h-tiles
  const int dt = bid & 15; bid >>= 4;   // 16 d-tiles
  const int r  = bid % NROT;
  const int n  = bid / NROT;

  const int d0 = dt * TD, h0 = ht * TH, w0 = wt * TW;

  // ---- rotation matrix #r, exactly replicating the reference enumeration ----
  // perms lexicographic, signs product([1,-1],repeat=3) order, keep det>0.
  int Rm[3][3];
  {
    const int perms[6][3] = {{0,1,2},{0,2,1},{1,0,2},{1,2,0},{2,0,1},{2,1,0}};
    const int psign[6]    = {1, -1, -1, 1, 1, -1};
    int count = 0;
    bool done = false;
    for (int pe = 0; pe < 6 && !done; ++pe) {
      for (int si = 0; si < 8 && !done; ++si) {
        const int s0 = (si & 4) ? -1 : 1;
        const int s1 = (si & 2) ? -1 : 1;
        const int s2 = (si & 1) ? -1 : 1;
        if (psign[pe] * s0 * s1 * s2 > 0) {
          if (count == r) {
            for (int a = 0; a < 3; ++a)
              for (int b = 0; b < 3; ++b) Rm[a][b] = 0;
            Rm[0][perms[pe][0]] = s0;
            Rm[1][perms[pe][1]] = s1;
            Rm[2][perms[pe][2]] = s2;
            done = true;
          }
          ++count;
        }
      }
    }
  }

  // ---- stage rotated weights for this r ----
  // wr[o][i][kd][kh][kw] = weight[o][i][sd][sh][sw],
  // (cx,cy,cz)=(kw-1,kh-1,kd-1); g = R*(cx,cy,cz); (sd,sh,sw)=(g2+1,g1+1,g0+1)
  for (int e = tid; e < COUT * CIN * 27; e += 256) {
    const int o   = e / (CIN * 27);
    const int rem = e - o * (CIN * 27);
    const int i   = rem / 27;
    const int t   = rem - i * 27;
    const int kd = t / 9;
    const int kh = (t - kd * 9) / 3;
    const int kw = t - kd * 9 - kh * 3;
    const int cx = kw - 1, cy = kh - 1, cz = kd - 1;
    const int g0 = Rm[0][0] * cx + Rm[0][1] * cy + Rm[0][2] * cz;
    const int g1 = Rm[1][0] * cx + Rm[1][1] * cy + Rm[1][2] * cz;
    const int g2 = Rm[2][0] * cx + Rm[2][1] * cy + Rm[2][2] * cz;
    const int sd = g2 + 1, sh = g1 + 1, sw = g0 + 1;
    lds_w[o][i][t] = weight[(o * CIN + i) * 27 + sd * 9 + sh * 3 + sw];
  }

  // ---- stage x tile (with zero halo) ----
  {
    const int NR = CIN * (TD + 2) * (TH + 2);  // 240 rows of 34 floats
    const float* xb = xin + (size_t)n * CIN * 64 * 64 * 64;
    for (int e = tid; e < NR * 34; e += 256) {
      const int row = e / 34;
      const int ww  = e - row * 34;
      const int i   = row / ((TD + 2) * (TH + 2));
      const int r2  = row - i * ((TD + 2) * (TH + 2));
      const int zz  = r2 / (TH + 2);
      const int yy  = r2 - zz * (TH + 2);
      const int gz = d0 - 1 + zz, gy = h0 - 1 + yy, gw = w0 - 1 + ww;
      float v = 0.f;
      if ((unsigned)gz < 64u && (unsigned)gy < 64u && (unsigned)gw < 64u)
        v = xb[((i * 64 + gz) * 64 + gy) * 64 + gw];
      lds_x[i][zz][yy][ww] = v;
    }
  }
  __syncthreads();

  const int tw  = tid & 7;         // 8 strips of 4 along w
  const int th_ = (tid >> 3) & 7;  // 8 along h
  const int td_ = tid >> 6;        // 4 along d (one wave per d-slice)

  float acc[COUT][4];
#pragma unroll
  for (int o = 0; o < COUT; ++o) {
    const float b = bias[o];
#pragma unroll
    for (int v = 0; v < 4; ++v) acc[o][v] = b;
  }

#pragma unroll 1
  for (int i = 0; i < CIN; ++i) {
    // register neighborhood: 3(d) x 3(h) x 6(w) around this thread's 4-voxel strip
    float vals[3][3][6];
#pragma unroll
    for (int a = 0; a < 3; ++a) {
#pragma unroll
      for (int b = 0; b < 3; ++b) {
        const float* p = &lds_x[i][td_ + a][th_ + b][tw * 4];
        const float4 q  = *(const float4*)p;       // 16B aligned
        const float2 q2 = *(const float2*)(p + 4); // 8B aligned
        vals[a][b][0] = q.x;  vals[a][b][1] = q.y;
        vals[a][b][2] = q.z;  vals[a][b][3] = q.w;
        vals[a][b][4] = q2.x; vals[a][b][5] = q2.y;
      }
    }
#pragma unroll
    for (int o = 0; o < COUT; ++o) {
      float wr_[28];
#pragma unroll
      for (int q = 0; q < 7; ++q)
        *(float4*)&wr_[q * 4] = *(const float4*)&lds_w[o][i][q * 4];  // broadcast reads
#pragma unroll
      for (int a = 0; a < 3; ++a)
#pragma unroll
        for (int b = 0; b < 3; ++b)
#pragma unroll
          for (int c = 0; c < 3; ++c) {
            const float wv = wr_[(a * 3 + b) * 3 + c];
#pragma unroll
            for (int v = 0; v < 4; ++v)
              acc[o][v] = fmaf(vals[a][b][v + c], wv, acc[o][v]);
          }
    }
  }

  // ---- write output: y[n][r][o][d][h][w] ----
  float* ob = out + (size_t)(n * NROT + r) * COUT * 262144;
  const int sp = (d0 + td_) * 4096 + (h0 + th_) * 64 + (w0 + tw * 4);
#pragma unroll
  for (int o = 0; o < COUT; ++o) {
    float4 st;
    st.x = acc[o][0]; st.y = acc[o][1]; st.z = acc[o][2]; st.w = acc[o][3];
    *(float4*)&ob[(size_t)o * 262144 + sp] = st;
  }
}

extern "C" void kernel_launch(void* const* d_in, const int* in_sizes, int n_in,
                              void* d_out, int out_size, void* d_ws, size_t ws_size,
                              hipStream_t stream) {
  const float* x = (const float*)d_in[0];
  const float* w = (const float*)d_in[1];
  const float* b = (const float*)d_in[2];
  float* out = (float*)d_out;
  // grid: 2(wt) * 8(ht) * 16(dt) * 24(r) * 2(n) = 12288 blocks
  convz3p24_kernel<<<dim3(12288), dim3(256), 0, stream>>>(x, w, b, out);
}

// Round 4
// 139.722 us; speedup vs baseline: 2.7215x; 2.7215x over previous
//
#include <hip/hip_runtime.h>
#include <cstdint>
#include <cstddef>

typedef __attribute__((ext_vector_type(8))) short short8;   // 8 bf16 (MFMA A/B frag)
typedef __attribute__((ext_vector_type(4))) float f32x4;    // MFMA C/D frag
typedef __attribute__((ext_vector_type(4))) unsigned int u32x4;

#define NROT 24
#define COUT 8
#define CIN  4
#define M_TOT 192        // 24*8
#define PLANE 262144     // 64^3
#define XD 3
#define XH 6
#define XW 66

__device__ __forceinline__ unsigned short f2bf(float f) {
  unsigned u = __builtin_bit_cast(unsigned, f);
  return (unsigned short)((u + 0x7FFFu + ((u >> 16) & 1u)) >> 16);  // RNE
}

__device__ __forceinline__ void rot_mat(int r, int Rm[3][3]) {
  // exactly the reference enumeration: perms lexicographic x signs [1,-1]^3, det>0
  const int perms[6][3] = {{0,1,2},{0,2,1},{1,0,2},{1,2,0},{2,0,1},{2,1,0}};
  const int psign[6] = {1,-1,-1,1,1,-1};
  int count = 0;
  for (int pe = 0; pe < 6; ++pe)
    for (int si = 0; si < 8; ++si) {
      const int s0 = (si & 4) ? -1 : 1;
      const int s1 = (si & 2) ? -1 : 1;
      const int s2 = (si & 1) ? -1 : 1;
      if (psign[pe] * s0 * s1 * s2 > 0) {
        if (count == r) {
          for (int a = 0; a < 3; ++a)
            for (int b = 0; b < 3; ++b) Rm[a][b] = 0;
          Rm[0][perms[pe][0]] = s0;
          Rm[1][perms[pe][1]] = s1;
          Rm[2][perms[pe][2]] = s2;
          return;
        }
        ++count;
      }
    }
}

// ---- pre-kernel: build A (rotated weights) in MFMA A-fragment layout, bf16 ----
// A[m][k]: m = r*8+o (row), k = tap*4 + i, tap=(kd*3+kh)*3+kw, K=108 padded to 128.
// Frag layout (16x16x32): lane holds A[row=lane&15][k = chunk*32 + (lane>>4)*8 + e].
// Abuf entry = (Mtile*4 + chunk)*64 + lane, 16 bytes (8 bf16).
__global__ void prep_A(const float* __restrict__ weight, unsigned short* __restrict__ Abuf) {
  const int tid = threadIdx.x;
  for (int ent = tid; ent < 12 * 4 * 64; ent += 256) {
    const int lane = ent & 63;
    const int mc = ent >> 6;
    const int Mtile = mc >> 2, chunk = mc & 3;
    const int m = Mtile * 16 + (lane & 15);
    const int r = m >> 3, o = m & 7;
    int Rm[3][3];
    rot_mat(r, Rm);
    unsigned short v8[8];
#pragma unroll
    for (int e = 0; e < 8; ++e) {
      const int k = chunk * 32 + (lane >> 4) * 8 + e;
      unsigned short hv = 0;
      if (k < 108) {
        const int t = k >> 2, i = k & 3;
        const int kd = t / 9, kh = (t / 3) % 3, kw = t % 3;
        const int cx = kw - 1, cy = kh - 1, cz = kd - 1;
        const int g0 = Rm[0][0] * cx + Rm[0][1] * cy + Rm[0][2] * cz;
        const int g1 = Rm[1][0] * cx + Rm[1][1] * cy + Rm[1][2] * cz;
        const int g2 = Rm[2][0] * cx + Rm[2][1] * cy + Rm[2][2] * cz;
        const int sd = g2 + 1, sh = g1 + 1, sw = g0 + 1;
        hv = f2bf(weight[(o * CIN + i) * 27 + sd * 9 + sh * 3 + sw]);
      }
      v8[e] = hv;
    }
    u32x4 packed;
    packed.x = (unsigned)v8[0] | ((unsigned)v8[1] << 16);
    packed.y = (unsigned)v8[2] | ((unsigned)v8[3] << 16);
    packed.z = (unsigned)v8[4] | ((unsigned)v8[5] << 16);
    packed.w = (unsigned)v8[6] | ((unsigned)v8[7] << 16);
    ((u32x4*)Abuf)[ent] = packed;
  }
}

// ---- main kernel: implicit-GEMM conv via mfma_f32_16x16x32_bf16 ----
// Block: 256 thr = 4 waves. Spatial block: fixed d, h0..h0+3, w 0..63 (16 n-tiles of 16 cols).
// Wave wv owns M-tiles wv*3 .. wv*3+2 (48 of 192 channels). x tile staged channels-last bf16.
__global__ __launch_bounds__(256)
void conv_mfma(const float* __restrict__ xin,
               const unsigned short* __restrict__ Abuf,
               const float* __restrict__ bias,
               float* __restrict__ out) {
  __shared__ uint2 xsv[XD * XH * XW];  // [zz][yy][ww] -> 4 bf16 (channels-last), 9.5 KB

  const int tid = threadIdx.x;
  int bid = blockIdx.x;
  const int ht = bid & 15; bid >>= 4;
  const int d  = bid & 63; bid >>= 6;
  const int n  = bid;            // 0..1
  const int h0 = ht * 4;

  // ---- stage x tile (zero halo), f32 -> bf16, channels-last ----
  const float* xb = xin + (size_t)n * CIN * PLANE;
  for (int v = tid; v < XD * XH * XW; v += 256) {
    const int ww = v % XW;
    const int rest = v / XW;
    const int yy = rest % XH;
    const int zz = rest / XH;
    const int gz = d - 1 + zz, gy = h0 - 1 + yy, gw = ww - 1;
    unsigned p0 = 0, p1 = 0;
    if ((unsigned)gz < 64u && (unsigned)gy < 64u && (unsigned)gw < 64u) {
      const int base = gz * 4096 + gy * 64 + gw;
      const unsigned a0 = f2bf(xb[base]);
      const unsigned a1 = f2bf(xb[base + PLANE]);
      const unsigned a2 = f2bf(xb[base + 2 * PLANE]);
      const unsigned a3 = f2bf(xb[base + 3 * PLANE]);
      p0 = a0 | (a1 << 16);
      p1 = a2 | (a3 << 16);
    }
    xsv[v] = make_uint2(p0, p1);
  }

  const int wv = tid >> 6;
  const int lane = tid & 63;
  const int lg = lane >> 4;      // lane-group 0..3
  const int col = lane & 15;

  // ---- load this wave's A-fragments (3 M-tiles x 4 chunks) into registers ----
  short8 afrag[3][4];
  const short8* Ab8 = (const short8*)Abuf;
#pragma unroll
  for (int j = 0; j < 3; ++j) {
    const int Mtile = wv * 3 + j;
#pragma unroll
    for (int c = 0; c < 4; ++c)
      afrag[j][c] = Ab8[(Mtile * 4 + c) * 64 + lane];
  }

  // bias per accumulator register: o = ((lg*4 + reg) & 7), independent of M-tile
  float bv[4];
#pragma unroll
  for (int reg = 0; reg < 4; ++reg) bv[reg] = bias[(lg * 4 + reg) & 7];

  // ---- precompute B-read voxel offsets (uint2-element units) per chunk/half ----
  int voff[4][2];
#pragma unroll
  for (int c = 0; c < 4; ++c)
#pragma unroll
    for (int hf = 0; hf < 2; ++hf) {
      int t = c * 8 + lg * 2 + hf;
      t = t > 26 ? 26 : t;              // clamp pad region to real data (A=0 there)
      const int kd = t / 9, kh = (t / 3) % 3, kw = t % 3;
      voff[c][hf] = (kd * XH + kh) * XW + col + kw;
    }

  __syncthreads();

  const int nbase = n * M_TOT;
  const int wv3 = wv * 3;

  // ---- 16 n-tiles: hh = nt>>2 (h offset), q = nt&3 (w group of 16) ----
#pragma unroll 1
  for (int nt = 0; nt < 16; ++nt) {
    const int hh = nt >> 2, q = nt & 3;
    const int dl = hh * XW + q * 16;

    f32x4 acc0 = {bv[0], bv[1], bv[2], bv[3]};
    f32x4 acc1 = acc0, acc2 = acc0;

#pragma unroll
    for (int c = 0; c < 4; ++c) {
      const uint2 lo = xsv[voff[c][0] + dl];
      const uint2 hi = xsv[voff[c][1] + dl];
      u32x4 bw;
      bw.x = lo.x; bw.y = lo.y; bw.z = hi.x; bw.w = hi.y;
      const short8 b = __builtin_bit_cast(short8, bw);
      acc0 = __builtin_amdgcn_mfma_f32_16x16x32_bf16(afrag[0][c], b, acc0, 0, 0, 0);
      acc1 = __builtin_amdgcn_mfma_f32_16x16x32_bf16(afrag[1][c], b, acc1, 0, 0, 0);
      acc2 = __builtin_amdgcn_mfma_f32_16x16x32_bf16(afrag[2][c], b, acc2, 0, 0, 0);
    }

    // ---- store: D[row][col], row = lg*4+reg -> channel m = Mtile*16 + row ----
    const int spbase = d * 4096 + (h0 + hh) * 64 + q * 16 + col;
    {
      const size_t p = (size_t)(nbase + (wv3 + 0) * 16 + lg * 4) * PLANE + spbase;
      out[p] = acc0[0]; out[p + PLANE] = acc0[1];
      out[p + 2 * PLANE] = acc0[2]; out[p + 3 * PLANE] = acc0[3];
    }
    {
      const size_t p = (size_t)(nbase + (wv3 + 1) * 16 + lg * 4) * PLANE + spbase;
      out[p] = acc1[0]; out[p + PLANE] = acc1[1];
      out[p + 2 * PLANE] = acc1[2]; out[p + 3 * PLANE] = acc1[3];
    }
    {
      const size_t p = (size_t)(nbase + (wv3 + 2) * 16 + lg * 4) * PLANE + spbase;
      out[p] = acc2[0]; out[p + PLANE] = acc2[1];
      out[p + 2 * PLANE] = acc2[2]; out[p + 3 * PLANE] = acc2[3];
    }
  }
}

extern "C" void kernel_launch(void* const* d_in, const int* in_sizes, int n_in,
                              void* d_out, int out_size, void* d_ws, size_t ws_size,
                              hipStream_t stream) {
  const float* x = (const float*)d_in[0];
  const float* w = (const float*)d_in[1];
  const float* b = (const float*)d_in[2];
  float* out = (float*)d_out;
  unsigned short* Abuf = (unsigned short*)d_ws;  // needs 12*4*64*16 = 49152 B

  prep_A<<<dim3(1), dim3(256), 0, stream>>>(w, Abuf);
  // grid: 16 h-tiles * 64 d * 2 n = 2048 blocks
  conv_mfma<<<dim3(2048), dim3(256), 0, stream>>>(x, Abuf, b, out);
}

// Round 8
// 116.592 us; speedup vs baseline: 3.2614x; 1.1984x over previous
//
#include <hip/hip_runtime.h>
#include <cstdint>
#include <cstddef>

typedef __attribute__((ext_vector_type(8))) short short8;   // 8 bf16 (MFMA A/B frag)
typedef __attribute__((ext_vector_type(4))) float f32x4;    // MFMA C/D frag
typedef __attribute__((ext_vector_type(4))) unsigned int u32x4;

#define NROT 24
#define COUT 8
#define CIN  4
#define M_TOT 192        // 24*8
#define PLANE 262144     // 64^3
#define XD 3
#define XH 6
#define XW 66

__device__ __forceinline__ unsigned short f2bf(float f) {
  unsigned u = __builtin_bit_cast(unsigned, f);
  return (unsigned short)((u + 0x7FFFu + ((u >> 16) & 1u)) >> 16);  // RNE
}

__device__ __forceinline__ void rot_mat(int r, int Rm[3][3]) {
  // exactly the reference enumeration: perms lexicographic x signs [1,-1]^3, det>0
  const int perms[6][3] = {{0,1,2},{0,2,1},{1,0,2},{1,2,0},{2,0,1},{2,1,0}};
  const int psign[6] = {1,-1,-1,1,1,-1};
  int count = 0;
  for (int pe = 0; pe < 6; ++pe)
    for (int si = 0; si < 8; ++si) {
      const int s0 = (si & 4) ? -1 : 1;
      const int s1 = (si & 2) ? -1 : 1;
      const int s2 = (si & 1) ? -1 : 1;
      if (psign[pe] * s0 * s1 * s2 > 0) {
        if (count == r) {
          for (int a = 0; a < 3; ++a)
            for (int b = 0; b < 3; ++b) Rm[a][b] = 0;
          Rm[0][perms[pe][0]] = s0;
          Rm[1][perms[pe][1]] = s1;
          Rm[2][perms[pe][2]] = s2;
          return;
        }
        ++count;
      }
    }
}

// ---- pre-kernel: build W_rot in MFMA fragment layout, bf16 ----
// W[m][k]: m = r*8+o, k = tap*4 + i, tap=(kd*3+kh)*3+kw, K=108 padded to 128.
// Frag layout: lane holds W[m=Mtile*16+(lane&15)][k = chunk*32 + (lane>>4)*8 + e].
// Abuf entry = (Mtile*4 + chunk)*64 + lane, 16 bytes (8 bf16).
__global__ void prep_A(const float* __restrict__ weight, unsigned short* __restrict__ Abuf) {
  const int tid = threadIdx.x;
  for (int ent = tid; ent < 12 * 4 * 64; ent += 256) {
    const int lane = ent & 63;
    const int mc = ent >> 6;
    const int Mtile = mc >> 2, chunk = mc & 3;
    const int m = Mtile * 16 + (lane & 15);
    const int r = m >> 3, o = m & 7;
    int Rm[3][3];
    rot_mat(r, Rm);
    unsigned short v8[8];
#pragma unroll
    for (int e = 0; e < 8; ++e) {
      const int k = chunk * 32 + (lane >> 4) * 8 + e;
      unsigned short hv = 0;
      if (k < 108) {
        const int t = k >> 2, i = k & 3;
        const int kd = t / 9, kh = (t / 3) % 3, kw = t % 3;
        const int cx = kw - 1, cy = kh - 1, cz = kd - 1;
        const int g0 = Rm[0][0] * cx + Rm[0][1] * cy + Rm[0][2] * cz;
        const int g1 = Rm[1][0] * cx + Rm[1][1] * cy + Rm[1][2] * cz;
        const int g2 = Rm[2][0] * cx + Rm[2][1] * cy + Rm[2][2] * cz;
        const int sd = g2 + 1, sh = g1 + 1, sw = g0 + 1;
        hv = f2bf(weight[(o * CIN + i) * 27 + sd * 9 + sh * 3 + sw]);
      }
      v8[e] = hv;
    }
    u32x4 packed;
    packed.x = (unsigned)v8[0] | ((unsigned)v8[1] << 16);
    packed.y = (unsigned)v8[2] | ((unsigned)v8[3] << 16);
    packed.z = (unsigned)v8[4] | ((unsigned)v8[5] << 16);
    packed.w = (unsigned)v8[6] | ((unsigned)v8[7] << 16);
    ((u32x4*)Abuf)[ent] = packed;
  }
}

// ---- main kernel: implicit-GEMM conv via mfma_f32_16x16x32_bf16, SWAPPED operands ----
// D = X . W^T : rows (lg*4+reg) = 4 consecutive w, cols (lane&15) = channel within Mtile.
// Each lane stores one dwordx4 per n-tile; channel-tile loop outermost -> 16 sequential
// write streams per wave, 1KB fully-ordered per channel per block.
__global__ __launch_bounds__(256)
void conv_mfma(const float* __restrict__ xin,
               const unsigned short* __restrict__ Abuf,
               const float* __restrict__ bias,
               float* __restrict__ out) {
  __shared__ uint2 xsv[XD * XH * XW];  // [zz][yy][ww] -> 4 bf16 (channels-last), 9.5 KB

  const int tid = threadIdx.x;
  int bid = blockIdx.x;
  const int ht = bid & 15; bid >>= 4;
  const int d  = bid & 63; bid >>= 6;
  const int n  = bid;            // 0..1
  const int h0 = ht * 4;

  // ---- stage x tile (zero halo), f32 -> bf16, channels-last ----
  const float* xb = xin + (size_t)n * CIN * PLANE;
  for (int v = tid; v < XD * XH * XW; v += 256) {
    const int ww = v % XW;
    const int rest = v / XW;
    const int yy = rest % XH;
    const int zz = rest / XH;
    const int gz = d - 1 + zz, gy = h0 - 1 + yy, gw = ww - 1;
    unsigned p0 = 0, p1 = 0;
    if ((unsigned)gz < 64u && (unsigned)gy < 64u && (unsigned)gw < 64u) {
      const int base = gz * 4096 + gy * 64 + gw;
      const unsigned a0 = f2bf(xb[base]);
      const unsigned a1 = f2bf(xb[base + PLANE]);
      const unsigned a2 = f2bf(xb[base + 2 * PLANE]);
      const unsigned a3 = f2bf(xb[base + 3 * PLANE]);
      p0 = a0 | (a1 << 16);
      p1 = a2 | (a3 << 16);
    }
    xsv[v] = make_uint2(p0, p1);
  }

  const int wv = tid >> 6;
  const int lane = tid & 63;
  const int lg = lane >> 4;      // lane-group 0..3
  const int col = lane & 15;

  // ---- load this wave's W-fragments (3 M-tiles x 4 chunks) into registers ----
  short8 afrag[3][4];
  const short8* Ab8 = (const short8*)Abuf;
#pragma unroll
  for (int j = 0; j < 3; ++j) {
    const int Mtile = wv * 3 + j;
#pragma unroll
    for (int c = 0; c < 4; ++c)
      afrag[j][c] = Ab8[(Mtile * 4 + c) * 64 + lane];
  }

  // swapped layout: channel = col (lane&15)  ->  one bias value per lane
  const float bv = bias[col & 7];

  // ---- precompute B(x)-read voxel offsets (uint2 units) per chunk/half ----
  // x-frag: lane's spatial index = col, k = c*32 + lg*8 + {0..7} (2 taps x 4 cin)
  int voff[4][2];
#pragma unroll
  for (int c = 0; c < 4; ++c)
#pragma unroll
    for (int hf = 0; hf < 2; ++hf) {
      int t = c * 8 + lg * 2 + hf;
      t = t > 26 ? 26 : t;              // clamp pad region to real data (W=0 there)
      const int kd = t / 9, kh = (t / 3) % 3, kw = t % 3;
      voff[c][hf] = (kd * XH + kh) * XW + col + kw;
    }

  __syncthreads();

  const int nbase = n * M_TOT;
  const int wv3 = wv * 3;

  // channel-tile outermost: per j, 16 write streams, each fully sequential
#pragma unroll
  for (int j = 0; j < 3; ++j) {
    // lane's output base: channel m = (wv3+j)*16 + col, spatial w = q*16 + lg*4 + reg
    float* op = out + (size_t)(nbase + (wv3 + j) * 16 + col) * PLANE
                    + d * 4096 + h0 * 64 + lg * 4;

#pragma unroll 1
    for (int hh = 0; hh < 4; ++hh) {
#pragma unroll
      for (int q = 0; q < 4; ++q) {
        const int dl = hh * XW + q * 16;

        f32x4 acc = {bv, bv, bv, bv};
#pragma unroll
        for (int c = 0; c < 4; ++c) {
          const uint2 lo = xsv[voff[c][0] + dl];
          const uint2 hi = xsv[voff[c][1] + dl];
          u32x4 bw;
          bw.x = lo.x; bw.y = lo.y; bw.z = hi.x; bw.w = hi.y;
          const short8 b = __builtin_bit_cast(short8, bw);
          // SWAPPED: D = X . W^T  (rows = spatial, cols = channels)
          acc = __builtin_amdgcn_mfma_f32_16x16x32_bf16(b, afrag[j][c], acc, 0, 0, 0);
        }

        // h row = h0 + hh  ->  offset hh*64 (BUGFIX: was hh*256, an OOB write)
        *(f32x4*)(op + hh * 64 + q * 16) = acc;   // dwordx4, 16 sequential streams/wave
      }
    }
  }
}

extern "C" void kernel_launch(void* const* d_in, const int* in_sizes, int n_in,
                              void* d_out, int out_size, void* d_ws, size_t ws_size,
                              hipStream_t stream) {
  const float* x = (const float*)d_in[0];
  const float* w = (const float*)d_in[1];
  const float* b = (const float*)d_in[2];
  float* out = (float*)d_out;
  unsigned short* Abuf = (unsigned short*)d_ws;  // needs 12*4*64*16 = 49152 B

  prep_A<<<dim3(1), dim3(256), 0, stream>>>(w, Abuf);
  // grid: 16 h-tiles * 64 d * 2 n = 2048 blocks
  conv_mfma<<<dim3(2048), dim3(256), 0, stream>>>(x, Abuf, b, out);
}

// Round 10
// 111.375 us; speedup vs baseline: 3.4142x; 1.0468x over previous
//
#include <hip/hip_runtime.h>
#include <cstdint>
#include <cstddef>

typedef __attribute__((ext_vector_type(8))) short short8;   // 8 bf16 (MFMA A/B frag)
typedef __attribute__((ext_vector_type(4))) float f32x4;    // MFMA C/D frag
typedef __attribute__((ext_vector_type(4))) unsigned int u32x4;

#define NROT 24
#define COUT 8
#define CIN  4
#define M_TOT 192        // 24*8
#define PLANE 262144     // 64^3
#define XD 3
#define XH 6
#define XW 66

__device__ __forceinline__ unsigned short f2bf(float f) {
  unsigned u = __builtin_bit_cast(unsigned, f);
  return (unsigned short)((u + 0x7FFFu + ((u >> 16) & 1u)) >> 16);  // RNE
}

__device__ __forceinline__ void rot_mat(int r, int Rm[3][3]) {
  // exactly the reference enumeration: perms lexicographic x signs [1,-1]^3, det>0
  const int perms[6][3] = {{0,1,2},{0,2,1},{1,0,2},{1,2,0},{2,0,1},{2,1,0}};
  const int psign[6] = {1,-1,-1,1,1,-1};
  int count = 0;
  for (int pe = 0; pe < 6; ++pe)
    for (int si = 0; si < 8; ++si) {
      const int s0 = (si & 4) ? -1 : 1;
      const int s1 = (si & 2) ? -1 : 1;
      const int s2 = (si & 1) ? -1 : 1;
      if (psign[pe] * s0 * s1 * s2 > 0) {
        if (count == r) {
          for (int a = 0; a < 3; ++a)
            for (int b = 0; b < 3; ++b) Rm[a][b] = 0;
          Rm[0][perms[pe][0]] = s0;
          Rm[1][perms[pe][1]] = s1;
          Rm[2][perms[pe][2]] = s2;
          return;
        }
        ++count;
      }
    }
}

// ---- pre-kernel: build W_rot in MFMA fragment layout, bf16 ----
// W[m][k]: m = r*8+o, k = tap*4 + i, tap=(kd*3+kh)*3+kw, K=108 padded to 128.
// Frag layout: lane holds W[m=Mtile*16+(lane&15)][k = chunk*32 + (lane>>4)*8 + e].
// Abuf entry = (Mtile*4 + chunk)*64 + lane, 16 bytes (8 bf16).
__global__ void prep_A(const float* __restrict__ weight, unsigned short* __restrict__ Abuf) {
  const int tid = threadIdx.x;
  for (int ent = tid; ent < 12 * 4 * 64; ent += 256) {
    const int lane = ent & 63;
    const int mc = ent >> 6;
    const int Mtile = mc >> 2, chunk = mc & 3;
    const int m = Mtile * 16 + (lane & 15);
    const int r = m >> 3, o = m & 7;
    int Rm[3][3];
    rot_mat(r, Rm);
    unsigned short v8[8];
#pragma unroll
    for (int e = 0; e < 8; ++e) {
      const int k = chunk * 32 + (lane >> 4) * 8 + e;
      unsigned short hv = 0;
      if (k < 108) {
        const int t = k >> 2, i = k & 3;
        const int kd = t / 9, kh = (t / 3) % 3, kw = t % 3;
        const int cx = kw - 1, cy = kh - 1, cz = kd - 1;
        const int g0 = Rm[0][0] * cx + Rm[0][1] * cy + Rm[0][2] * cz;
        const int g1 = Rm[1][0] * cx + Rm[1][1] * cy + Rm[1][2] * cz;
        const int g2 = Rm[2][0] * cx + Rm[2][1] * cy + Rm[2][2] * cz;
        const int sd = g2 + 1, sh = g1 + 1, sw = g0 + 1;
        hv = f2bf(weight[(o * CIN + i) * 27 + sd * 9 + sh * 3 + sw]);
      }
      v8[e] = hv;
    }
    u32x4 packed;
    packed.x = (unsigned)v8[0] | ((unsigned)v8[1] << 16);
    packed.y = (unsigned)v8[2] | ((unsigned)v8[3] << 16);
    packed.z = (unsigned)v8[4] | ((unsigned)v8[5] << 16);
    packed.w = (unsigned)v8[6] | ((unsigned)v8[7] << 16);
    ((u32x4*)Abuf)[ent] = packed;
  }
}

// ---- main kernel: implicit-GEMM conv via mfma_f32_16x16x32_bf16, SWAPPED operands ----
// D = X . W^T. Epilogue bounces each j-tile's accs through per-wave LDS so every
// global store is ONE fully-contiguous 1KB burst for a single channel (4 h-rows x 64 w),
// issued channel-major sequential. Write->read phases pinned with lgkmcnt(0) +
// sched_barrier(0) (guide rule #18: hipcc reorders LDS ops across predicated blocks).
__global__ __launch_bounds__(256)
void conv_mfma(const float* __restrict__ xin,
               const unsigned short* __restrict__ Abuf,
               const float* __restrict__ bias,
               float* __restrict__ out) {
  __shared__ uint2 xsv[XD * XH * XW];      // 9.5 KB input tile (channels-last bf16)
  __shared__ float obuf[4][4][4][68];      // per-wave bounce: [wv][ch&3][hh][w pad 68] = 17 KB

  const int tid = threadIdx.x;
  int bid = blockIdx.x;
  const int ht = bid & 15; bid >>= 4;
  const int d  = bid & 63; bid >>= 6;
  const int n  = bid;            // 0..1
  const int h0 = ht * 4;

  // ---- stage x tile (zero halo), f32 -> bf16, channels-last ----
  const float* xb = xin + (size_t)n * CIN * PLANE;
  for (int v = tid; v < XD * XH * XW; v += 256) {
    const int ww = v % XW;
    const int rest = v / XW;
    const int yy = rest % XH;
    const int zz = rest / XH;
    const int gz = d - 1 + zz, gy = h0 - 1 + yy, gw = ww - 1;
    unsigned p0 = 0, p1 = 0;
    if ((unsigned)gz < 64u && (unsigned)gy < 64u && (unsigned)gw < 64u) {
      const int base = gz * 4096 + gy * 64 + gw;
      const unsigned a0 = f2bf(xb[base]);
      const unsigned a1 = f2bf(xb[base + PLANE]);
      const unsigned a2 = f2bf(xb[base + 2 * PLANE]);
      const unsigned a3 = f2bf(xb[base + 3 * PLANE]);
      p0 = a0 | (a1 << 16);
      p1 = a2 | (a3 << 16);
    }
    xsv[v] = make_uint2(p0, p1);
  }

  const int wv = tid >> 6;
  const int lane = tid & 63;
  const int lg = lane >> 4;      // lane-group 0..3
  const int col = lane & 15;

  // swapped layout: channel = col (lane&15)  ->  one bias value per lane
  const float bv = bias[col & 7];

  // ---- precompute B(x)-read voxel offsets (uint2 units) per chunk/half ----
  int voff[4][2];
#pragma unroll
  for (int c = 0; c < 4; ++c)
#pragma unroll
    for (int hf = 0; hf < 2; ++hf) {
      int t = c * 8 + lg * 2 + hf;
      t = t > 26 ? 26 : t;              // clamp pad region to real data (W=0 there)
      const int kd = t / 9, kh = (t / 3) % 3, kw = t % 3;
      voff[c][hf] = (kd * XH + kh) * XW + col + kw;
    }

  __syncthreads();

  const int nbase = n * M_TOT;
  const int wv3 = wv * 3;
  const short8* Ab8 = (const short8*)Abuf;
  const int spb = d * 4096 + h0 * 64;    // block's spatial base (1KB-aligned per channel)

#pragma unroll 1
  for (int j = 0; j < 3; ++j) {
    // W-fragments for this channel-tile (Abuf is tiny & L2-hot; reload saves VGPRs)
    short8 af[4];
#pragma unroll
    for (int c = 0; c < 4; ++c)
      af[c] = Ab8[((wv3 + j) * 4 + c) * 64 + lane];

    // ---- compute 16 n-tiles into registers ----
    f32x4 acc16[16];
#pragma unroll
    for (int hh = 0; hh < 4; ++hh) {
#pragma unroll
      for (int q = 0; q < 4; ++q) {
        const int dl = hh * XW + q * 16;
        f32x4 acc = {bv, bv, bv, bv};
#pragma unroll
        for (int c = 0; c < 4; ++c) {
          const uint2 lo = xsv[voff[c][0] + dl];
          const uint2 hi = xsv[voff[c][1] + dl];
          u32x4 bw;
          bw.x = lo.x; bw.y = lo.y; bw.z = hi.x; bw.w = hi.y;
          const short8 b = __builtin_bit_cast(short8, bw);
          acc = __builtin_amdgcn_mfma_f32_16x16x32_bf16(b, af[c], acc, 0, 0, 0);
        }
        acc16[hh * 4 + q] = acc;
      }
    }

    // ---- bounce through LDS; store 1KB-contiguous per channel ----
    // acc16[hh*4+q][reg] = channel col, h row h0+hh, w = q*16 + lg*4 + reg
#pragma unroll
    for (int g = 0; g < 4; ++g) {
      if ((col >> 2) == g) {
#pragma unroll
        for (int hq = 0; hq < 16; ++hq)
          *(f32x4*)&obuf[wv][col & 3][hq >> 2][(hq & 3) * 16 + lg * 4] = acc16[hq];
      }
      // pin write-phase completion before reads (wave-local; obuf is wv-sliced)
      __builtin_amdgcn_sched_barrier(0);
      asm volatile("s_waitcnt lgkmcnt(0)" ::: "memory");
      __builtin_amdgcn_sched_barrier(0);
#pragma unroll
      for (int cc = 0; cc < 4; ++cc) {
        const f32x4 v = *(const f32x4*)&obuf[wv][cc][lane >> 4][(lane & 15) * 4];
        const int ch = g * 4 + cc;
        float* p = out + (size_t)(nbase + (wv3 + j) * 16 + ch) * PLANE + spb + lane * 4;
        *(f32x4*)p = v;   // 64 lanes x 16B = ONE contiguous 1KB burst
      }
      // pin read-phase completion before next g overwrites the buffer
      __builtin_amdgcn_sched_barrier(0);
      asm volatile("s_waitcnt lgkmcnt(0)" ::: "memory");
      __builtin_amdgcn_sched_barrier(0);
    }
  }
}

extern "C" void kernel_launch(void* const* d_in, const int* in_sizes, int n_in,
                              void* d_out, int out_size, void* d_ws, size_t ws_size,
                              hipStream_t stream) {
  const float* x = (const float*)d_in[0];
  const float* w = (const float*)d_in[1];
  const float* b = (const float*)d_in[2];
  float* out = (float*)d_out;
  unsigned short* Abuf = (unsigned short*)d_ws;  // needs 12*4*64*16 = 49152 B

  prep_A<<<dim3(1), dim3(256), 0, stream>>>(w, Abuf);
  // grid: 16 h-tiles * 64 d * 2 n = 2048 blocks
  conv_mfma<<<dim3(2048), dim3(256), 0, stream>>>(x, Abuf, b, out);
}

// Round 11
// 97.450 us; speedup vs baseline: 3.9021x; 1.1429x over previous
//
#include <hip/hip_runtime.h>
#include <cstdint>
#include <cstddef>

typedef __attribute__((ext_vector_type(8))) short short8;   // 8 bf16 (MFMA A/B frag)
typedef __attribute__((ext_vector_type(4))) float f32x4;    // MFMA C/D frag
typedef __attribute__((ext_vector_type(2))) float f32x2;
typedef __attribute__((ext_vector_type(4))) unsigned int u32x4;

#define NROT 24
#define COUT 8
#define CIN  4
#define M_TOT 192        // 24*8
#define PLANE 262144     // 64^3
#define XD 3
#define XH 6
#define XW 66

__device__ __forceinline__ unsigned short f2bf(float f) {
  unsigned u = __builtin_bit_cast(unsigned, f);
  return (unsigned short)((u + 0x7FFFu + ((u >> 16) & 1u)) >> 16);  // RNE
}

__device__ __forceinline__ void rot_mat(int r, int Rm[3][3]) {
  // exactly the reference enumeration: perms lexicographic x signs [1,-1]^3, det>0
  const int perms[6][3] = {{0,1,2},{0,2,1},{1,0,2},{1,2,0},{2,0,1},{2,1,0}};
  const int psign[6] = {1,-1,-1,1,1,-1};
  int count = 0;
  for (int pe = 0; pe < 6; ++pe)
    for (int si = 0; si < 8; ++si) {
      const int s0 = (si & 4) ? -1 : 1;
      const int s1 = (si & 2) ? -1 : 1;
      const int s2 = (si & 1) ? -1 : 1;
      if (psign[pe] * s0 * s1 * s2 > 0) {
        if (count == r) {
          for (int a = 0; a < 3; ++a)
            for (int b = 0; b < 3; ++b) Rm[a][b] = 0;
          Rm[0][perms[pe][0]] = s0;
          Rm[1][perms[pe][1]] = s1;
          Rm[2][perms[pe][2]] = s2;
          return;
        }
        ++count;
      }
    }
}

// ---- pre-kernel: build W_rot in MFMA fragment layout, bf16 ----
// 12 blocks x 256 thr: one entry per thread (was 1 block serializing the GPU).
__global__ void prep_A(const float* __restrict__ weight, unsigned short* __restrict__ Abuf) {
  const int ent = blockIdx.x * 256 + threadIdx.x;
  if (ent >= 12 * 4 * 64) return;
  const int lane = ent & 63;
  const int mc = ent >> 6;
  const int Mtile = mc >> 2, chunk = mc & 3;
  const int m = Mtile * 16 + (lane & 15);
  const int r = m >> 3, o = m & 7;
  int Rm[3][3];
  rot_mat(r, Rm);
  unsigned short v8[8];
#pragma unroll
  for (int e = 0; e < 8; ++e) {
    const int k = chunk * 32 + (lane >> 4) * 8 + e;
    unsigned short hv = 0;
    if (k < 108) {
      const int t = k >> 2, i = k & 3;
      const int kd = t / 9, kh = (t / 3) % 3, kw = t % 3;
      const int cx = kw - 1, cy = kh - 1, cz = kd - 1;
      const int g0 = Rm[0][0] * cx + Rm[0][1] * cy + Rm[0][2] * cz;
      const int g1 = Rm[1][0] * cx + Rm[1][1] * cy + Rm[1][2] * cz;
      const int g2 = Rm[2][0] * cx + Rm[2][1] * cy + Rm[2][2] * cz;
      const int sd = g2 + 1, sh = g1 + 1, sw = g0 + 1;
      hv = f2bf(weight[(o * CIN + i) * 27 + sd * 9 + sh * 3 + sw]);
    }
    v8[e] = hv;
  }
  u32x4 packed;
  packed.x = (unsigned)v8[0] | ((unsigned)v8[1] << 16);
  packed.y = (unsigned)v8[2] | ((unsigned)v8[3] << 16);
  packed.z = (unsigned)v8[4] | ((unsigned)v8[5] << 16);
  packed.w = (unsigned)v8[6] | ((unsigned)v8[7] << 16);
  ((u32x4*)Abuf)[ent] = packed;
}

// ---- main kernel: implicit-GEMM conv via mfma_f32_16x16x32_bf16, swapped operands ----
// Per j-tile, TWO half-epilogues (8 n-tiles each): acc8 = 32 VGPR (occupancy), obuf
// parity-double-buffered so each g-phase needs only ONE lgkmcnt(0) (RAW; WAR covered
// by next phase's drain). Stores: 512B contiguous per channel, channel-major.
__global__ __launch_bounds__(256)
void conv_mfma(const float* __restrict__ xin,
               const unsigned short* __restrict__ Abuf,
               const float* __restrict__ bias,
               float* __restrict__ out) {
  __shared__ uint2 xsv[XD * XH * XW];        // 9.5 KB input tile (channels-last bf16)
  __shared__ float obuf[4][2][4][2][68];     // [wv][parity][cc][hh][w pad 68] = 17 KB

  const int tid = threadIdx.x;
  int bid = blockIdx.x;
  const int ht = bid & 15; bid >>= 4;
  const int d  = bid & 63; bid >>= 6;
  const int n  = bid;            // 0..1
  const int h0 = ht * 4;

  // ---- stage x tile (zero halo), f32 -> bf16, channels-last ----
  const float* xb = xin + (size_t)n * CIN * PLANE;
  for (int v = tid; v < XD * XH * XW; v += 256) {
    const int ww = v % XW;
    const int rest = v / XW;
    const int yy = rest % XH;
    const int zz = rest / XH;
    const int gz = d - 1 + zz, gy = h0 - 1 + yy, gw = ww - 1;
    unsigned p0 = 0, p1 = 0;
    if ((unsigned)gz < 64u && (unsigned)gy < 64u && (unsigned)gw < 64u) {
      const int base = gz * 4096 + gy * 64 + gw;
      const unsigned a0 = f2bf(xb[base]);
      const unsigned a1 = f2bf(xb[base + PLANE]);
      const unsigned a2 = f2bf(xb[base + 2 * PLANE]);
      const unsigned a3 = f2bf(xb[base + 3 * PLANE]);
      p0 = a0 | (a1 << 16);
      p1 = a2 | (a3 << 16);
    }
    xsv[v] = make_uint2(p0, p1);
  }

  const int wv = tid >> 6;
  const int lane = tid & 63;
  const int lg = lane >> 4;      // lane-group 0..3
  const int col = lane & 15;

  // swapped layout: channel = col (lane&15)  ->  one bias value per lane
  const float bv = bias[col & 7];

  // ---- precompute B(x)-read voxel offsets (uint2 units) per chunk/half ----
  int voff[4][2];
#pragma unroll
  for (int c = 0; c < 4; ++c)
#pragma unroll
    for (int hf = 0; hf < 2; ++hf) {
      int t = c * 8 + lg * 2 + hf;
      t = t > 26 ? 26 : t;              // clamp pad region to real data (W=0 there)
      const int kd = t / 9, kh = (t / 3) % 3, kw = t % 3;
      voff[c][hf] = (kd * XH + kh) * XW + col + kw;
    }

  __syncthreads();

  const int nbase = n * M_TOT;
  const int wv3 = wv * 3;
  const short8* Ab8 = (const short8*)Abuf;
  const int spb = d * 4096 + h0 * 64;    // block's spatial base

#pragma unroll 1
  for (int j = 0; j < 3; ++j) {
    // W-fragments for this channel-tile (Abuf is tiny & L2-hot)
    short8 af[4];
#pragma unroll
    for (int c = 0; c < 4; ++c)
      af[c] = Ab8[((wv3 + j) * 4 + c) * 64 + lane];

#pragma unroll 1
    for (int half = 0; half < 2; ++half) {
      // ---- compute 8 n-tiles (2 h-rows x 4 w-groups) ----
      f32x4 acc8[8];
#pragma unroll
      for (int hq = 0; hq < 8; ++hq) {
        const int hh = half * 2 + (hq >> 2);
        const int q = hq & 3;
        const int dl = hh * XW + q * 16;
        f32x4 acc = {bv, bv, bv, bv};
#pragma unroll
        for (int c = 0; c < 4; ++c) {
          const uint2 lo = xsv[voff[c][0] + dl];
          const uint2 hi = xsv[voff[c][1] + dl];
          u32x4 bw;
          bw.x = lo.x; bw.y = lo.y; bw.z = hi.x; bw.w = hi.y;
          const short8 b = __builtin_bit_cast(short8, bw);
          acc = __builtin_amdgcn_mfma_f32_16x16x32_bf16(b, af[c], acc, 0, 0, 0);
        }
        acc8[hq] = acc;
      }

      // ---- bounce through LDS; 512B contiguous store per channel ----
      // acc8[hq][reg] = channel col, h = h0 + half*2 + (hq>>2), w = (hq&3)*16 + lg*4 + reg
#pragma unroll
      for (int g = 0; g < 4; ++g) {
        const int par = g & 1;
        if ((col >> 2) == g) {
#pragma unroll
          for (int hq = 0; hq < 8; ++hq)
            *(f32x4*)&obuf[wv][par][col & 3][hq >> 2][(hq & 3) * 16 + lg * 4] = acc8[hq];
        }
        // RAW drain (wave-local; WAR for parity par is covered by the g-1 drain)
        __builtin_amdgcn_sched_barrier(0);
        asm volatile("s_waitcnt lgkmcnt(0)" ::: "memory");
        __builtin_amdgcn_sched_barrier(0);
#pragma unroll
        for (int cc = 0; cc < 4; ++cc) {
          // 128 floats of channel cc: lane reads f32x2 -> one contiguous 512B burst
          const f32x2 v = *(const f32x2*)&obuf[wv][par][cc][lane >> 5][(lane & 31) * 2];
          const int ch = g * 4 + cc;
          float* p = out + (size_t)(nbase + (wv3 + j) * 16 + ch) * PLANE
                         + spb + half * 128 + lane * 2;
          *(f32x2*)p = v;
        }
      }
    }
  }
}

extern "C" void kernel_launch(void* const* d_in, const int* in_sizes, int n_in,
                              void* d_out, int out_size, void* d_ws, size_t ws_size,
                              hipStream_t stream) {
  const float* x = (const float*)d_in[0];
  const float* w = (const float*)d_in[1];
  const float* b = (const float*)d_in[2];
  float* out = (float*)d_out;
  unsigned short* Abuf = (unsigned short*)d_ws;  // needs 12*4*64*16 = 49152 B

  prep_A<<<dim3(12), dim3(256), 0, stream>>>(w, Abuf);
  // grid: 16 h-tiles * 64 d * 2 n = 2048 blocks
  conv_mfma<<<dim3(2048), dim3(256), 0, stream>>>(x, Abuf, b, out);
}

// Round 12
// 89.653 us; speedup vs baseline: 4.2414x; 1.0870x over previous
//
#include <hip/hip_runtime.h>
#include <cstdint>
#include <cstddef>

typedef __attribute__((ext_vector_type(8))) short short8;   // 8 bf16 (MFMA A/B frag)
typedef __attribute__((ext_vector_type(4))) float f32x4;    // MFMA C/D frag
typedef __attribute__((ext_vector_type(4))) unsigned int u32x4;

#define NROT 24
#define COUT 8
#define CIN  4
#define M_TOT 192        // 24*8
#define PLANE 262144     // 64^3
#define XD 3
#define XH 6
#define XW 66

__device__ __forceinline__ unsigned short f2bf(float f) {
  unsigned u = __builtin_bit_cast(unsigned, f);
  return (unsigned short)((u + 0x7FFFu + ((u >> 16) & 1u)) >> 16);  // RNE
}

__device__ __forceinline__ void rot_mat(int r, int Rm[3][3]) {
  // exactly the reference enumeration: perms lexicographic x signs [1,-1]^3, det>0
  const int perms[6][3] = {{0,1,2},{0,2,1},{1,0,2},{1,2,0},{2,0,1},{2,1,0}};
  const int psign[6] = {1,-1,-1,1,1,-1};
  int count = 0;
  for (int pe = 0; pe < 6; ++pe)
    for (int si = 0; si < 8; ++si) {
      const int s0 = (si & 4) ? -1 : 1;
      const int s1 = (si & 2) ? -1 : 1;
      const int s2 = (si & 1) ? -1 : 1;
      if (psign[pe] * s0 * s1 * s2 > 0) {
        if (count == r) {
          for (int a = 0; a < 3; ++a)
            for (int b = 0; b < 3; ++b) Rm[a][b] = 0;
          Rm[0][perms[pe][0]] = s0;
          Rm[1][perms[pe][1]] = s1;
          Rm[2][perms[pe][2]] = s2;
          return;
        }
        ++count;
      }
    }
}

// ---- pre-kernel: build W_rot in MFMA fragment layout, bf16 (12 blocks, 1 ent/thread) ----
__global__ void prep_A(const float* __restrict__ weight, unsigned short* __restrict__ Abuf) {
  const int ent = blockIdx.x * 256 + threadIdx.x;
  if (ent >= 12 * 4 * 64) return;
  const int lane = ent & 63;
  const int mc = ent >> 6;
  const int Mtile = mc >> 2, chunk = mc & 3;
  const int m = Mtile * 16 + (lane & 15);
  const int r = m >> 3, o = m & 7;
  int Rm[3][3];
  rot_mat(r, Rm);
  unsigned short v8[8];
#pragma unroll
  for (int e = 0; e < 8; ++e) {
    const int k = chunk * 32 + (lane >> 4) * 8 + e;
    unsigned short hv = 0;
    if (k < 108) {
      const int t = k >> 2, i = k & 3;
      const int kd = t / 9, kh = (t / 3) % 3, kw = t % 3;
      const int cx = kw - 1, cy = kh - 1, cz = kd - 1;
      const int g0 = Rm[0][0] * cx + Rm[0][1] * cy + Rm[0][2] * cz;
      const int g1 = Rm[1][0] * cx + Rm[1][1] * cy + Rm[1][2] * cz;
      const int g2 = Rm[2][0] * cx + Rm[2][1] * cy + Rm[2][2] * cz;
      const int sd = g2 + 1, sh = g1 + 1, sw = g0 + 1;
      hv = f2bf(weight[(o * CIN + i) * 27 + sd * 9 + sh * 3 + sw]);
    }
    v8[e] = hv;
  }
  u32x4 packed;
  packed.x = (unsigned)v8[0] | ((unsigned)v8[1] << 16);
  packed.y = (unsigned)v8[2] | ((unsigned)v8[3] << 16);
  packed.z = (unsigned)v8[4] | ((unsigned)v8[5] << 16);
  packed.w = (unsigned)v8[6] | ((unsigned)v8[7] << 16);
  ((u32x4*)Abuf)[ent] = packed;
}

// ---- main kernel: implicit-GEMM conv, swapped MFMA operands, per-hh epilogue ----
// acc4 (16 VGPR) + tiny obuf (4.3 KB) -> ~7 blocks/CU (vs 5) for deeper HBM-write
// queue coverage. Per g-phase: 4 channels x 256B contiguous segments, channel-major.
__global__ __launch_bounds__(256)
void conv_mfma(const float* __restrict__ xin,
               const unsigned short* __restrict__ Abuf,
               const float* __restrict__ bias,
               float* __restrict__ out) {
  __shared__ uint2 xsv[XD * XH * XW];    // 9.3 KB input tile (channels-last bf16)
  __shared__ float obuf[4][4][68];       // [wv][ch&3][w pad 68] = 4.3 KB

  const int tid = threadIdx.x;
  int bid = blockIdx.x;
  const int ht = bid & 15; bid >>= 4;
  const int d  = bid & 63; bid >>= 6;
  const int n  = bid;            // 0..1
  const int h0 = ht * 4;

  // ---- stage x tile (zero halo), f32 -> bf16, channels-last ----
  const float* xb = xin + (size_t)n * CIN * PLANE;
  for (int v = tid; v < XD * XH * XW; v += 256) {
    const int ww = v % XW;
    const int rest = v / XW;
    const int yy = rest % XH;
    const int zz = rest / XH;
    const int gz = d - 1 + zz, gy = h0 - 1 + yy, gw = ww - 1;
    unsigned p0 = 0, p1 = 0;
    if ((unsigned)gz < 64u && (unsigned)gy < 64u && (unsigned)gw < 64u) {
      const int base = gz * 4096 + gy * 64 + gw;
      const unsigned a0 = f2bf(xb[base]);
      const unsigned a1 = f2bf(xb[base + PLANE]);
      const unsigned a2 = f2bf(xb[base + 2 * PLANE]);
      const unsigned a3 = f2bf(xb[base + 3 * PLANE]);
      p0 = a0 | (a1 << 16);
      p1 = a2 | (a3 << 16);
    }
    xsv[v] = make_uint2(p0, p1);
  }

  const int wv = tid >> 6;
  const int lane = tid & 63;
  const int lg = lane >> 4;      // lane-group 0..3
  const int col = lane & 15;

  // swapped layout: channel = col (lane&15)  ->  one bias value per lane
  const float bv = bias[col & 7];

  // ---- precompute B(x)-read voxel offsets (uint2 units) per chunk/half ----
  int voff[4][2];
#pragma unroll
  for (int c = 0; c < 4; ++c)
#pragma unroll
    for (int hf = 0; hf < 2; ++hf) {
      int t = c * 8 + lg * 2 + hf;
      t = t > 26 ? 26 : t;              // clamp pad region to real data (W=0 there)
      const int kd = t / 9, kh = (t / 3) % 3, kw = t % 3;
      voff[c][hf] = (kd * XH + kh) * XW + col + kw;
    }

  __syncthreads();

  const int nbase = n * M_TOT;
  const int wv3 = wv * 3;
  const short8* Ab8 = (const short8*)Abuf;
  const int spb = d * 4096 + h0 * 64;    // block's spatial base
  const int cc = lane >> 4;              // reader channel-sub
  const int off = (lane & 15) * 4;       // reader w offset

#pragma unroll 1
  for (int j = 0; j < 3; ++j) {
    // W-fragments for this channel-tile (Abuf is tiny & L2-hot)
    short8 af[4];
#pragma unroll
    for (int c = 0; c < 4; ++c)
      af[c] = Ab8[((wv3 + j) * 4 + c) * 64 + lane];

    const size_t jch = (size_t)(nbase + (wv3 + j) * 16);

#pragma unroll 1
    for (int hh = 0; hh < 4; ++hh) {
      // ---- compute one h-row: 4 n-tiles ----
      f32x4 acc[4];
#pragma unroll
      for (int q = 0; q < 4; ++q) {
        const int dl = hh * XW + q * 16;
        f32x4 a = {bv, bv, bv, bv};
#pragma unroll
        for (int c = 0; c < 4; ++c) {
          const uint2 lo = xsv[voff[c][0] + dl];
          const uint2 hi = xsv[voff[c][1] + dl];
          u32x4 bw;
          bw.x = lo.x; bw.y = lo.y; bw.z = hi.x; bw.w = hi.y;
          const short8 b = __builtin_bit_cast(short8, bw);
          a = __builtin_amdgcn_mfma_f32_16x16x32_bf16(b, af[c], a, 0, 0, 0);
        }
        acc[q] = a;
      }

      // ---- per-hh bounce: 4 g-phases, each 4 channels x 256B contiguous ----
      // acc[q][reg]: channel col, h = h0+hh, w = q*16 + lg*4 + reg
#pragma unroll
      for (int g = 0; g < 4; ++g) {
        if ((col >> 2) == g) {
#pragma unroll
          for (int q = 0; q < 4; ++q)
            *(f32x4*)&obuf[wv][col & 3][q * 16 + lg * 4] = acc[q];
        }
        // RAW drain (wave-local LDS ops are processed in order; WAR to next g's
        // writes is safe same-wave after this drain + sched pin)
        __builtin_amdgcn_sched_barrier(0);
        asm volatile("s_waitcnt lgkmcnt(0)" ::: "memory");
        __builtin_amdgcn_sched_barrier(0);
        const f32x4 v = *(const f32x4*)&obuf[wv][cc][off];
        float* p = out + (jch + g * 4 + cc) * PLANE + spb + hh * 64 + off;
        *(f32x4*)p = v;
        __builtin_amdgcn_sched_barrier(0);
      }
    }
  }
}

extern "C" void kernel_launch(void* const* d_in, const int* in_sizes, int n_in,
                              void* d_out, int out_size, void* d_ws, size_t ws_size,
                              hipStream_t stream) {
  const float* x = (const float*)d_in[0];
  const float* w = (const float*)d_in[1];
  const float* b = (const float*)d_in[2];
  float* out = (float*)d_out;
  unsigned short* Abuf = (unsigned short*)d_ws;  // needs 12*4*64*16 = 49152 B

  prep_A<<<dim3(12), dim3(256), 0, stream>>>(w, Abuf);
  // grid: 16 h-tiles * 64 d * 2 n = 2048 blocks
  conv_mfma<<<dim3(2048), dim3(256), 0, stream>>>(x, Abuf, b, out);
}